// Round 3
// baseline (996.163 us; speedup 1.0000x reference)
//
#include <hip/hip_runtime.h>
#include <hip/hip_bf16.h>
#include <cstdint>
#include <cstddef>

// ---- problem constants (DeepSeek-V3 MoE config) ----
#define T_TOK 1024
#define H_DIM 1024
#define I_DIM 704
#define E_NUM 64
#define TOPK 8
#define NGRP 8
#define GSIZE 8          // E_NUM / NGRP
#define TOPKG 4
#define SI_DIM 1408
#define RSCALE 2.5f
#define NSLOT (T_TOK * TOPK)   // 8192

#define AP 72            // LDS row pitch in bf16 elems (144 B rows, 16B-aligned, 2-way max aliasing)

typedef short bf16x8 __attribute__((ext_vector_type(8)));
typedef float f32x4 __attribute__((ext_vector_type(4)));

__device__ inline unsigned pk2(float x, float y) {
    __hip_bfloat162 h2 = __float22bfloat162_rn(make_float2(x, y));
    unsigned u; __builtin_memcpy(&u, &h2, 4); return u;
}
__device__ inline unsigned short bf1(float x) {
    __hip_bfloat16 h = __float2bfloat16(x);
    unsigned short u; __builtin_memcpy(&u, &h, 2); return u;
}
__device__ inline uint4 pkq(float4 a, float4 b) {
    return make_uint4(pk2(a.x, a.y), pk2(a.z, a.w), pk2(b.x, b.y), pk2(b.z, b.w));
}
__device__ inline bf16x8 cvt8(float4 a, float4 b) {
    unsigned u[4] = {pk2(a.x, a.y), pk2(a.z, a.w), pk2(b.x, b.y), pk2(b.z, b.w)};
    bf16x8 r; __builtin_memcpy(&r, u, 16); return r;
}

// ---------------- routing ----------------
__global__ __launch_bounds__(64) void route_kernel(
    const float* __restrict__ x, const float* __restrict__ gw, const float* __restrict__ gb,
    int* __restrict__ counts, int* __restrict__ tk_idx, float* __restrict__ tk_w)
{
    const int t = blockIdx.x;
    __shared__ float xs[H_DIM];
    __shared__ float raw[E_NUM];
    __shared__ float sc[E_NUM];
    __shared__ float masked[E_NUM];
    __shared__ float gsc[NGRP];
    const int tid = threadIdx.x;

    const float4* xrow = (const float4*)(x + (size_t)t * H_DIM);
    for (int i = tid; i < H_DIM / 4; i += 64) ((float4*)xs)[i] = xrow[i];
    __syncthreads();

    float a = 0.f;
    const float* w = gw + (size_t)tid * H_DIM;
    for (int h = 0; h < H_DIM; h += 4) {
        float4 w4 = *(const float4*)(w + h);
        a += xs[h] * w4.x + xs[h+1] * w4.y + xs[h+2] * w4.z + xs[h+3] * w4.w;
    }
    float s = 1.f / (1.f + expf(-a));
    raw[tid] = s;
    sc[tid] = s + gb[tid];
    __syncthreads();

    if (tid == 0) {
        for (int g = 0; g < NGRP; ++g) {
            float m1 = -1e30f, m2 = -1e30f;
            for (int j = 0; j < GSIZE; ++j) {
                float v = sc[g * GSIZE + j];
                if (v > m1) { m2 = m1; m1 = v; }
                else if (v > m2) { m2 = v; }
            }
            gsc[g] = m1 + m2;
        }
        bool gsel[NGRP];
        for (int g = 0; g < NGRP; ++g) gsel[g] = false;
        for (int k = 0; k < TOPKG; ++k) {
            int best = -1; float bv = -1e30f;
            for (int g = 0; g < NGRP; ++g)
                if (!gsel[g] && gsc[g] > bv) { bv = gsc[g]; best = g; }
            gsel[best] = true;
        }
        for (int e = 0; e < E_NUM; ++e)
            masked[e] = gsel[e / GSIZE] ? sc[e] : 0.0f;
        int idx[TOPK];
        float wsum = 0.f;
        for (int k = 0; k < TOPK; ++k) {
            int best = 0; float bv = -1e30f;
            for (int e = 0; e < E_NUM; ++e)
                if (masked[e] > bv) { bv = masked[e]; best = e; }
            masked[best] = -1e30f;
            idx[k] = best;
            wsum += raw[best];
        }
        float inv = RSCALE / (wsum + 1e-20f);
        for (int k = 0; k < TOPK; ++k) {
            tk_idx[t * TOPK + k] = idx[k];
            tk_w[t * TOPK + k] = raw[idx[k]] * inv;
            atomicAdd(&counts[idx[k]], 1);
        }
    }
}

__global__ void zero_kernel(int* counts, int* fillc)
{
    int i = threadIdx.x;
    if (i < E_NUM) { counts[i] = 0; fillc[i] = 0; }
}

__global__ void scan_kernel(const int* __restrict__ counts, int* __restrict__ offs)
{
    if (threadIdx.x == 0) {
        int acc = 0;
        for (int e = 0; e < E_NUM; ++e) { offs[e] = acc; acc += counts[e]; }
    }
}

__global__ void fill_kernel(const int* __restrict__ tk_idx, const float* __restrict__ tk_w,
                            const int* __restrict__ offs, int* __restrict__ fillc,
                            int* __restrict__ tok_list, float* __restrict__ w_list,
                            int* __restrict__ tk_pos)
{
    int t = blockIdx.x * blockDim.x + threadIdx.x;
    if (t >= T_TOK) return;
    for (int k = 0; k < TOPK; ++k) {
        int e = tk_idx[t * TOPK + k];
        int pos = offs[e] + atomicAdd(&fillc[e], 1);
        tok_list[pos] = t;
        w_list[pos] = tk_w[t * TOPK + k];
        tk_pos[t * TOPK + k] = pos;
    }
}

// ---------------- routed gate/up: FLIPPED — weights stream global->reg, tokens in LDS ----------------
// D[m = I-row][n = slot].  Block: 32 I-rows x 128 slots.  Waves 0,1 = gate rows 0-15/16-31,
// waves 2,3 = up rows 0-15/16-31.  SwiGLU combine via LDS exchange at epilogue.
__global__ __launch_bounds__(256, 4) void gateup_routed_mfma(
    const float* __restrict__ x, const float* __restrict__ Wg, const float* __restrict__ Wu,
    const int* __restrict__ offs, const int* __restrict__ counts,
    const int* __restrict__ tok_list, const float* __restrict__ w_list,
    unsigned short* __restrict__ act)
{
    const int e = blockIdx.z;
    const int cnt = counts[e];
    const int s0 = blockIdx.y * 128;
    if (s0 >= cnt) return;
    const int off = offs[e];
    const int i0 = blockIdx.x * 32;

    __shared__ unsigned short Bs[2][128 * AP];   // token tile, double-buffered (36 KB)
    __shared__ int toks[128];
    __shared__ float wts[128];

    const int tid = threadIdx.x;
    if (tid < 128) {
        int s = s0 + tid;
        toks[tid] = (s < cnt) ? tok_list[off + s] : 0;
        wts[tid]  = (s < cnt) ? w_list[off + s] : 0.f;
    }
    __syncthreads();

    const int lane = tid & 63;
    const int wv = tid >> 6;
    const int lr = lane & 15;
    const int lq = lane >> 4;
    const int rhalf = wv & 1;      // which 16-row half of the I-tile
    const int isup = wv >> 1;      // 0 = gate, 1 = up

    // this lane's weight row (exclusive to this wave): A-frag layout row=lane&15, k=(lane>>4)*8
    const float* wp = (isup ? Wu : Wg) + (size_t)e * I_DIM * H_DIM
                    + (size_t)(i0 + rhalf * 16 + lr) * H_DIM + lq * 8;

    // token staging: thread -> (row = tid>>1, 32-col half)
    const int trow = tid >> 1;
    const int tc = (tid & 1) * 32;
    const float* tp = x + (size_t)toks[trow] * H_DIM + tc;

    f32x4 acc[8];
    #pragma unroll
    for (int j = 0; j < 8; ++j) acc[j] = (f32x4){0.f, 0.f, 0.f, 0.f};

    float4 pw0, pw1, pw2, pw3;   // weight prefetch: 8 f32 per ks-slice
    float4 tf[8];                // token prefetch: 32 f32

    // prologue: k0 = 0
    pw0 = *(const float4*)(wp + 0);
    pw1 = *(const float4*)(wp + 4);
    pw2 = *(const float4*)(wp + 32);
    pw3 = *(const float4*)(wp + 36);
    #pragma unroll
    for (int j = 0; j < 8; ++j) tf[j] = *(const float4*)(tp + j * 4);
    #pragma unroll
    for (int c = 0; c < 4; ++c)
        *(uint4*)&Bs[0][trow * AP + tc + c * 8] = pkq(tf[2*c], tf[2*c+1]);
    __syncthreads();

    int buf = 0;
    for (int k0 = 0; k0 < H_DIM; k0 += 64) {
        const int kn = k0 + 64;
        // convert current weights (loaded last iter) to MFMA frags
        bf16x8 af0 = cvt8(pw0, pw1);
        bf16x8 af1 = cvt8(pw2, pw3);
        // issue next tile's loads (hide under MFMA + barrier; only 48 f32/thread live)
        if (kn < H_DIM) {
            pw0 = *(const float4*)(wp + kn);
            pw1 = *(const float4*)(wp + kn + 4);
            pw2 = *(const float4*)(wp + kn + 32);
            pw3 = *(const float4*)(wp + kn + 36);
            #pragma unroll
            for (int j = 0; j < 8; ++j) tf[j] = *(const float4*)(tp + kn + j * 4);
        }
        #pragma unroll
        for (int ks = 0; ks < 2; ++ks) {
            bf16x8 a = ks ? af1 : af0;
            #pragma unroll
            for (int nj = 0; nj < 8; ++nj) {
                bf16x8 b = *(const bf16x8*)&Bs[buf][(nj * 16 + lr) * AP + ks * 32 + lq * 8];
                acc[nj] = __builtin_amdgcn_mfma_f32_16x16x32_bf16(a, b, acc[nj], 0, 0, 0);
            }
        }
        if (kn >= H_DIM) break;
        // write next token tile to the other buffer; one barrier per k-step
        #pragma unroll
        for (int c = 0; c < 4; ++c)
            *(uint4*)&Bs[buf ^ 1][trow * AP + tc + c * 8] = pkq(tf[2*c], tf[2*c+1]);
        __syncthreads();
        buf ^= 1;
    }

    // ---- epilogue: gate waves hand their acc to up waves via LDS (aliased over Bs) ----
    __syncthreads();
    float* gex = (float*)&Bs[0][0];   // 2 * 8 * 64 * 4 f32 = 16 KB <= 36 KB
    if (!isup) {
        #pragma unroll
        for (int nj = 0; nj < 8; ++nj)
            *(f32x4*)&gex[((rhalf * 8 + nj) * 64 + lane) * 4] = acc[nj];
    }
    __syncthreads();
    if (isup) {
        #pragma unroll
        for (int nj = 0; nj < 8; ++nj) {
            int sl = nj * 16 + lr;                 // slot within tile (D col = lane&15)
            f32x4 g = *(const f32x4*)&gex[((rhalf * 8 + nj) * 64 + lane) * 4];
            float w = wts[sl];
            unsigned short o[4];
            #pragma unroll
            for (int r = 0; r < 4; ++r) {
                float gg = g[r];
                float a = w * (gg / (1.f + __expf(-gg))) * acc[nj][r];
                o[r] = bf1(a);
            }
            if (s0 + sl < cnt) {
                // 4 consecutive I-rows at fixed slot -> one 8 B store
                uint2 pkd = make_uint2((unsigned)o[0] | ((unsigned)o[1] << 16),
                                       (unsigned)o[2] | ((unsigned)o[3] << 16));
                *(uint2*)(act + (size_t)(off + s0 + sl) * I_DIM + i0 + rhalf * 16 + lq * 4) = pkd;
            }
        }
    }
}

// ---------------- routed down proj: FLIPPED — Wd streams global->reg, act tile in LDS ----------------
// D[m = H-row][n = slot].  Block: 64 H-rows x 128 slots, wave wv owns rows wv*16..+16.
__global__ __launch_bounds__(256, 4) void down_routed_mfma(
    const unsigned short* __restrict__ act, const float* __restrict__ Wd,
    const int* __restrict__ offs, const int* __restrict__ counts,
    float* __restrict__ slot_out)
{
    const int e = blockIdx.z;
    const int cnt = counts[e];
    const int s0 = blockIdx.y * 128;
    if (s0 >= cnt) return;
    const int off = offs[e];
    const int h0 = blockIdx.x * 64;

    __shared__ unsigned short Bs[2][128 * AP];   // act tile, double-buffered

    const int tid = threadIdx.x;
    const int lane = tid & 63;
    const int wv = tid >> 6;
    const int lr = lane & 15;
    const int lq = lane >> 4;

    const float* wp = Wd + (size_t)e * H_DIM * I_DIM
                    + (size_t)(h0 + wv * 16 + lr) * I_DIM + lq * 8;

    // act staging: thread -> (slot row = tid>>1, 32-col half); rows contiguous in act
    int srow = s0 + (tid >> 1);
    if (srow > cnt - 1) srow = cnt - 1;          // clamp: pad rows masked at store
    const unsigned short* ap = act + (size_t)(off + srow) * I_DIM + (tid & 1) * 32;

    f32x4 acc[8];
    #pragma unroll
    for (int j = 0; j < 8; ++j) acc[j] = (f32x4){0.f, 0.f, 0.f, 0.f};

    float4 pw0, pw1, pw2, pw3;
    uint4 tf[4];   // 64 B of bf16 act per thread

    pw0 = *(const float4*)(wp + 0);
    pw1 = *(const float4*)(wp + 4);
    pw2 = *(const float4*)(wp + 32);
    pw3 = *(const float4*)(wp + 36);
    #pragma unroll
    for (int j = 0; j < 4; ++j) tf[j] = *(const uint4*)(ap + j * 8);
    #pragma unroll
    for (int j = 0; j < 4; ++j)
        *(uint4*)&Bs[0][(tid >> 1) * AP + (tid & 1) * 32 + j * 8] = tf[j];
    __syncthreads();

    int buf = 0;
    for (int k0 = 0; k0 < I_DIM; k0 += 64) {
        const int kn = k0 + 64;
        bf16x8 af0 = cvt8(pw0, pw1);
        bf16x8 af1 = cvt8(pw2, pw3);
        if (kn < I_DIM) {
            pw0 = *(const float4*)(wp + kn);
            pw1 = *(const float4*)(wp + kn + 4);
            pw2 = *(const float4*)(wp + kn + 32);
            pw3 = *(const float4*)(wp + kn + 36);
            #pragma unroll
            for (int j = 0; j < 4; ++j) tf[j] = *(const uint4*)(ap + kn + j * 8);
        }
        #pragma unroll
        for (int ks = 0; ks < 2; ++ks) {
            bf16x8 a = ks ? af1 : af0;
            #pragma unroll
            for (int nj = 0; nj < 8; ++nj) {
                bf16x8 b = *(const bf16x8*)&Bs[buf][(nj * 16 + lr) * AP + ks * 32 + lq * 8];
                acc[nj] = __builtin_amdgcn_mfma_f32_16x16x32_bf16(a, b, acc[nj], 0, 0, 0);
            }
        }
        if (kn >= I_DIM) break;
        #pragma unroll
        for (int j = 0; j < 4; ++j)
            *(uint4*)&Bs[buf ^ 1][(tid >> 1) * AP + (tid & 1) * 32 + j * 8] = tf[j];
        __syncthreads();
        buf ^= 1;
    }

    // store: 4 consecutive H-rows at fixed slot -> float4
    #pragma unroll
    for (int nj = 0; nj < 8; ++nj) {
        int sl = nj * 16 + lr;
        if (s0 + sl < cnt)
            *(f32x4*)(slot_out + (size_t)(off + s0 + sl) * H_DIM + h0 + wv * 16 + lq * 4) = acc[nj];
    }
}

// ---------------- combine: out[t] += sum_k slot_out[pos(t,k)] ----------------
__global__ __launch_bounds__(256) void combine_kernel(
    const float* __restrict__ slot_out, const int* __restrict__ tk_pos,
    float* __restrict__ out)
{
    const int t = blockIdx.x;
    __shared__ int pos[TOPK];
    if (threadIdx.x < TOPK) pos[threadIdx.x] = tk_pos[t * TOPK + threadIdx.x];
    __syncthreads();
    const int i = threadIdx.x;   // 256 threads x float4 = 1024 floats
    float4 a = ((const float4*)(out + (size_t)t * H_DIM))[i];
    #pragma unroll
    for (int k = 0; k < TOPK; ++k) {
        float4 v = ((const float4*)(slot_out + (size_t)pos[k] * H_DIM))[i];
        a.x += v.x; a.y += v.y; a.z += v.z; a.w += v.w;
    }
    ((float4*)(out + (size_t)t * H_DIM))[i] = a;
}

// ---------------- shared expert gate/up: MFMA dense (round-0 proven body) ----------------
__global__ __launch_bounds__(256) void gateup_shared_mfma(
    const float* __restrict__ x, const float* __restrict__ Sg, const float* __restrict__ Su,
    unsigned short* __restrict__ sact)
{
    const int m0 = blockIdx.y * 128;
    const int n0 = blockIdx.x * 64;

    __shared__ unsigned short As[128 * AP];
    __shared__ unsigned short Bg[64 * AP];
    __shared__ unsigned short Bu[64 * AP];

    const int tid = threadIdx.x;
    const int lane = tid & 63;
    const int wv = tid >> 6;
    const int lr = lane & 15;
    const int lq = lane >> 4;

    f32x4 accg[2][4], accu[2][4];
    #pragma unroll
    for (int i = 0; i < 2; ++i)
        #pragma unroll
        for (int j = 0; j < 4; ++j) {
            accg[i][j] = (f32x4){0.f, 0.f, 0.f, 0.f};
            accu[i][j] = (f32x4){0.f, 0.f, 0.f, 0.f};
        }

    const float* gp = Sg + (size_t)n0 * H_DIM;
    const float* up = Su + (size_t)n0 * H_DIM;
    const int ar = tid >> 4;
    const int ac = (tid & 15) * 4;

    for (int k0 = 0; k0 < H_DIM; k0 += 64) {
        #pragma unroll
        for (int p = 0; p < 8; ++p) {
            int r = ar + p * 16;
            float4 v = *(const float4*)(x + (size_t)(m0 + r) * H_DIM + k0 + ac);
            *(uint2*)&As[r * AP + ac] = make_uint2(pk2(v.x, v.y), pk2(v.z, v.w));
        }
        #pragma unroll
        for (int p = 0; p < 4; ++p) {
            int r = ar + p * 16;
            float4 g = *(const float4*)(gp + (size_t)r * H_DIM + k0 + ac);
            *(uint2*)&Bg[r * AP + ac] = make_uint2(pk2(g.x, g.y), pk2(g.z, g.w));
            float4 u = *(const float4*)(up + (size_t)r * H_DIM + k0 + ac);
            *(uint2*)&Bu[r * AP + ac] = make_uint2(pk2(u.x, u.y), pk2(u.z, u.w));
        }
        __syncthreads();
        #pragma unroll
        for (int ks = 0; ks < 2; ++ks) {
            bf16x8 a0 = *(const bf16x8*)&As[(wv * 32 + lr) * AP + ks * 32 + lq * 8];
            bf16x8 a1 = *(const bf16x8*)&As[(wv * 32 + 16 + lr) * AP + ks * 32 + lq * 8];
            #pragma unroll
            for (int nj = 0; nj < 4; ++nj) {
                bf16x8 bg = *(const bf16x8*)&Bg[(nj * 16 + lr) * AP + ks * 32 + lq * 8];
                bf16x8 bu = *(const bf16x8*)&Bu[(nj * 16 + lr) * AP + ks * 32 + lq * 8];
                accg[0][nj] = __builtin_amdgcn_mfma_f32_16x16x32_bf16(a0, bg, accg[0][nj], 0, 0, 0);
                accg[1][nj] = __builtin_amdgcn_mfma_f32_16x16x32_bf16(a1, bg, accg[1][nj], 0, 0, 0);
                accu[0][nj] = __builtin_amdgcn_mfma_f32_16x16x32_bf16(a0, bu, accu[0][nj], 0, 0, 0);
                accu[1][nj] = __builtin_amdgcn_mfma_f32_16x16x32_bf16(a1, bu, accu[1][nj], 0, 0, 0);
            }
        }
        __syncthreads();
    }

    #pragma unroll
    for (int mi = 0; mi < 2; ++mi) {
        #pragma unroll
        for (int r = 0; r < 4; ++r) {
            int trow = m0 + wv * 32 + mi * 16 + lq * 4 + r;
            unsigned short* sp = sact + (size_t)trow * SI_DIM + n0 + lr;
            #pragma unroll
            for (int nj = 0; nj < 4; ++nj) {
                float g = accg[mi][nj][r];
                float u = accu[mi][nj][r];
                float a = (g / (1.f + __expf(-g))) * u;
                sp[nj * 16] = bf1(a);
            }
        }
    }
}

// ---------------- shared expert down proj: MFMA dense (round-0 proven body) ----------------
__global__ __launch_bounds__(256) void down_shared_mfma(
    const unsigned short* __restrict__ sact, const float* __restrict__ Sd,
    float* __restrict__ out)
{
    const int m0 = blockIdx.y * 128;
    const int n0 = blockIdx.x * 64;

    __shared__ unsigned short As[128 * AP];
    __shared__ unsigned short Bs[64 * AP];

    const int tid = threadIdx.x;
    const int lane = tid & 63;
    const int wv = tid >> 6;
    const int lr = lane & 15;
    const int lq = lane >> 4;

    f32x4 acc[2][4];
    #pragma unroll
    for (int i = 0; i < 2; ++i)
        #pragma unroll
        for (int j = 0; j < 4; ++j)
            acc[i][j] = (f32x4){0.f, 0.f, 0.f, 0.f};

    const float* wp = Sd + (size_t)n0 * SI_DIM;
    const int ar = tid >> 4;
    const int ac = (tid & 15) * 4;

    for (int k0 = 0; k0 < SI_DIM; k0 += 64) {
        #pragma unroll
        for (int p = 0; p < 8; ++p) {
            int r = ar + p * 16;
            uint2 v = *(const uint2*)(sact + (size_t)(m0 + r) * SI_DIM + k0 + ac);
            *(uint2*)&As[r * AP + ac] = v;
        }
        #pragma unroll
        for (int p = 0; p < 4; ++p) {
            int r = ar + p * 16;
            float4 w4 = *(const float4*)(wp + (size_t)r * SI_DIM + k0 + ac);
            *(uint2*)&Bs[r * AP + ac] = make_uint2(pk2(w4.x, w4.y), pk2(w4.z, w4.w));
        }
        __syncthreads();
        #pragma unroll
        for (int ks = 0; ks < 2; ++ks) {
            bf16x8 a0 = *(const bf16x8*)&As[(wv * 32 + lr) * AP + ks * 32 + lq * 8];
            bf16x8 a1 = *(const bf16x8*)&As[(wv * 32 + 16 + lr) * AP + ks * 32 + lq * 8];
            #pragma unroll
            for (int nj = 0; nj < 4; ++nj) {
                bf16x8 b = *(const bf16x8*)&Bs[(nj * 16 + lr) * AP + ks * 32 + lq * 8];
                acc[0][nj] = __builtin_amdgcn_mfma_f32_16x16x32_bf16(a0, b, acc[0][nj], 0, 0, 0);
                acc[1][nj] = __builtin_amdgcn_mfma_f32_16x16x32_bf16(a1, b, acc[1][nj], 0, 0, 0);
            }
        }
        __syncthreads();
    }

    #pragma unroll
    for (int mi = 0; mi < 2; ++mi) {
        #pragma unroll
        for (int r = 0; r < 4; ++r) {
            int trow = m0 + wv * 32 + mi * 16 + lq * 4 + r;
            float* op = out + (size_t)trow * H_DIM + n0 + lr;
            #pragma unroll
            for (int nj = 0; nj < 4; ++nj)
                op[nj * 16] = acc[mi][nj][r];
        }
    }
}

// ---------------- launch ----------------
extern "C" void kernel_launch(void* const* d_in, const int* in_sizes, int n_in,
                              void* d_out, int out_size, void* d_ws, size_t ws_size,
                              hipStream_t stream)
{
    const float* x  = (const float*)d_in[0];
    const float* gw = (const float*)d_in[1];
    const float* gb = (const float*)d_in[2];
    const float* Wg = (const float*)d_in[3];
    const float* Wu = (const float*)d_in[4];
    const float* Wd = (const float*)d_in[5];
    const float* Sg = (const float*)d_in[6];
    const float* Su = (const float*)d_in[7];
    const float* Sd = (const float*)d_in[8];
    float* out = (float*)d_out;

    // workspace layout (16B-aligned chunks first)
    float* slot_out = (float*)d_ws;                                   // 8192*1024 f32  (33.5 MB)
    unsigned short* act  = (unsigned short*)(slot_out + (size_t)NSLOT * H_DIM);  // 8192*704 bf16
    unsigned short* sact = act + (size_t)NSLOT * I_DIM;               // 1024*1408 bf16
    int* counts   = (int*)(sact + (size_t)T_TOK * SI_DIM);            // 64
    int* fillc    = counts + 64;                                      // 64
    int* offs     = fillc + 64;                                       // 64
    int* tk_idx   = offs + 64;                                        // 8192
    float* tk_w   = (float*)(tk_idx + NSLOT);                         // 8192
    int* tok_list = (int*)(tk_w + NSLOT);                             // 8192
    float* w_list = (float*)(tok_list + NSLOT);                       // 8192
    int* tk_pos   = (int*)(w_list + NSLOT);                           // 8192

    zero_kernel<<<1, 64, 0, stream>>>(counts, fillc);
    route_kernel<<<T_TOK, 64, 0, stream>>>(x, gw, gb, counts, tk_idx, tk_w);
    scan_kernel<<<1, 64, 0, stream>>>(counts, offs);
    fill_kernel<<<4, 256, 0, stream>>>(tk_idx, tk_w, offs, fillc, tok_list, w_list, tk_pos);

    gateup_routed_mfma<<<dim3(22, 8, 64), 256, 0, stream>>>(x, Wg, Wu, offs, counts, tok_list, w_list, act);
    gateup_shared_mfma<<<dim3(22, 8, 1), 256, 0, stream>>>(x, Sg, Su, sact);
    down_shared_mfma<<<dim3(16, 8, 1), 256, 0, stream>>>(sact, Sd, out);
    down_routed_mfma<<<dim3(16, 8, 64), 256, 0, stream>>>(act, Wd, offs, counts, slot_out);
    combine_kernel<<<T_TOK, 256, 0, stream>>>(slot_out, tk_pos, out);
}

// Round 4
// 941.599 us; speedup vs baseline: 1.0579x; 1.0579x over previous
//
#include <hip/hip_runtime.h>
#include <hip/hip_bf16.h>
#include <cstdint>
#include <cstddef>

// ---- problem constants (DeepSeek-V3 MoE config) ----
#define T_TOK 1024
#define H_DIM 1024
#define I_DIM 704
#define E_NUM 64
#define TOPK 8
#define NGRP 8
#define GSIZE 8          // E_NUM / NGRP
#define TOPKG 4
#define SI_DIM 1408
#define RSCALE 2.5f
#define NSLOT (T_TOK * TOPK)   // 8192

#define AP 72            // LDS row pitch in bf16 elems (144 B rows, 16B-aligned)

// blocked layouts (RMW-free stores):
//   act_blk  : [22 i-tiles of 32][NSLOT][32]  bf16
//   slot_blk : [16 h-tiles of 64][NSLOT][64]  f32
#define ABLK(it, s) ((size_t)(it) * NSLOT * 32 + (size_t)(s) * 32)
#define SBLK(ht, s) ((size_t)(ht) * NSLOT * 64 + (size_t)(s) * 64)

typedef short bf16x8 __attribute__((ext_vector_type(8)));
typedef float f32x4 __attribute__((ext_vector_type(4)));

__device__ inline unsigned pk2(float x, float y) {
    __hip_bfloat162 h2 = __float22bfloat162_rn(make_float2(x, y));
    unsigned u; __builtin_memcpy(&u, &h2, 4); return u;
}
__device__ inline unsigned short bf1(float x) {
    __hip_bfloat16 h = __float2bfloat16(x);
    unsigned short u; __builtin_memcpy(&u, &h, 2); return u;
}
__device__ inline uint4 pkq(float4 a, float4 b) {
    return make_uint4(pk2(a.x, a.y), pk2(a.z, a.w), pk2(b.x, b.y), pk2(b.z, b.w));
}
__device__ inline bf16x8 cvt8(float4 a, float4 b) {
    unsigned u[4] = {pk2(a.x, a.y), pk2(a.z, a.w), pk2(b.x, b.y), pk2(b.z, b.w)};
    bf16x8 r; __builtin_memcpy(&r, u, 16); return r;
}
__device__ inline void wave_barrier() {
    // publish LDS writes, but leave global prefetch loads in flight (no vmcnt(0) drain)
    asm volatile("s_waitcnt lgkmcnt(0)" ::: "memory");
    __builtin_amdgcn_s_barrier();
}

// ---------------- routing ----------------
__global__ __launch_bounds__(64) void route_kernel(
    const float* __restrict__ x, const float* __restrict__ gw, const float* __restrict__ gb,
    int* __restrict__ counts, int* __restrict__ tk_idx, float* __restrict__ tk_w)
{
    const int t = blockIdx.x;
    __shared__ float xs[H_DIM];
    __shared__ float raw[E_NUM];
    __shared__ float sc[E_NUM];
    __shared__ float masked[E_NUM];
    __shared__ float gsc[NGRP];
    const int tid = threadIdx.x;

    const float4* xrow = (const float4*)(x + (size_t)t * H_DIM);
    for (int i = tid; i < H_DIM / 4; i += 64) ((float4*)xs)[i] = xrow[i];
    __syncthreads();

    float a = 0.f;
    const float* w = gw + (size_t)tid * H_DIM;
    for (int h = 0; h < H_DIM; h += 4) {
        float4 w4 = *(const float4*)(w + h);
        a += xs[h] * w4.x + xs[h+1] * w4.y + xs[h+2] * w4.z + xs[h+3] * w4.w;
    }
    float s = 1.f / (1.f + expf(-a));
    raw[tid] = s;
    sc[tid] = s + gb[tid];
    __syncthreads();

    if (tid == 0) {
        for (int g = 0; g < NGRP; ++g) {
            float m1 = -1e30f, m2 = -1e30f;
            for (int j = 0; j < GSIZE; ++j) {
                float v = sc[g * GSIZE + j];
                if (v > m1) { m2 = m1; m1 = v; }
                else if (v > m2) { m2 = v; }
            }
            gsc[g] = m1 + m2;
        }
        bool gsel[NGRP];
        for (int g = 0; g < NGRP; ++g) gsel[g] = false;
        for (int k = 0; k < TOPKG; ++k) {
            int best = -1; float bv = -1e30f;
            for (int g = 0; g < NGRP; ++g)
                if (!gsel[g] && gsc[g] > bv) { bv = gsc[g]; best = g; }
            gsel[best] = true;
        }
        for (int e = 0; e < E_NUM; ++e)
            masked[e] = gsel[e / GSIZE] ? sc[e] : 0.0f;
        int idx[TOPK];
        float wsum = 0.f;
        for (int k = 0; k < TOPK; ++k) {
            int best = 0; float bv = -1e30f;
            for (int e = 0; e < E_NUM; ++e)
                if (masked[e] > bv) { bv = masked[e]; best = e; }
            masked[best] = -1e30f;
            idx[k] = best;
            wsum += raw[best];
        }
        float inv = RSCALE / (wsum + 1e-20f);
        for (int k = 0; k < TOPK; ++k) {
            tk_idx[t * TOPK + k] = idx[k];
            tk_w[t * TOPK + k] = raw[idx[k]] * inv;
            atomicAdd(&counts[idx[k]], 1);
        }
    }
}

__global__ void zero_kernel(int* counts, int* fillc)
{
    int i = threadIdx.x;
    if (i < E_NUM) { counts[i] = 0; fillc[i] = 0; }
}

__global__ void scan_kernel(const int* __restrict__ counts, int* __restrict__ offs)
{
    if (threadIdx.x == 0) {
        int acc = 0;
        for (int e = 0; e < E_NUM; ++e) { offs[e] = acc; acc += counts[e]; }
    }
}

__global__ void fill_kernel(const int* __restrict__ tk_idx, const float* __restrict__ tk_w,
                            const int* __restrict__ offs, int* __restrict__ fillc,
                            int* __restrict__ tok_list, float* __restrict__ w_list,
                            int* __restrict__ tk_pos)
{
    int t = blockIdx.x * blockDim.x + threadIdx.x;
    if (t >= T_TOK) return;
    for (int k = 0; k < TOPK; ++k) {
        int e = tk_idx[t * TOPK + k];
        int pos = offs[e] + atomicAdd(&fillc[e], 1);
        tok_list[pos] = t;
        w_list[pos] = tk_w[t * TOPK + k];
        tk_pos[t * TOPK + k] = pos;
    }
}

// ---------------- routed gate/up: weights global->reg, tokens LDS dbuf, 2-deep pipeline ----------------
// D[m = I-row][n = slot].  Block: 32 I-rows x 128 slots.  Waves 0,1 = gate rows 0-15/16-31,
// waves 2,3 = up rows 0-15/16-31.  SwiGLU combine via LDS exchange at epilogue.
// act written in blocked layout [i-tile][slot][32] -> contiguous 32B-sector stores (no RMW).
__global__ __launch_bounds__(256, 4) void gateup_routed_mfma(
    const float* __restrict__ x, const float* __restrict__ Wg, const float* __restrict__ Wu,
    const int* __restrict__ offs, const int* __restrict__ counts,
    const int* __restrict__ tok_list, const float* __restrict__ w_list,
    unsigned short* __restrict__ act)
{
    const int e = blockIdx.z;
    const int cnt = counts[e];
    const int s0 = blockIdx.y * 128;
    if (s0 >= cnt) return;
    const int off = offs[e];
    const int i0 = blockIdx.x * 32;
    const int NK = H_DIM / 64;   // 16

    __shared__ unsigned short Bs[2][128 * AP];   // token tile, double-buffered (36 KB)
    __shared__ int toks[128];
    __shared__ float wts[128];

    const int tid = threadIdx.x;
    if (tid < 128) {
        int s = s0 + tid;
        toks[tid] = (s < cnt) ? tok_list[off + s] : 0;
        wts[tid]  = (s < cnt) ? w_list[off + s] : 0.f;
    }
    __syncthreads();

    const int lane = tid & 63;
    const int wv = tid >> 6;
    const int lr = lane & 15;
    const int lq = lane >> 4;
    const int rhalf = wv & 1;      // which 16-row half of the I-tile
    const int isup = wv >> 1;      // 0 = gate, 1 = up

    // wave-exclusive weight row; A-frag layout row=lane&15, k=(lane>>4)*8
    const float* wp = (isup ? Wu : Wg) + (size_t)e * I_DIM * H_DIM
                    + (size_t)(i0 + rhalf * 16 + lr) * H_DIM + lq * 8;

    // token staging: thread -> (row = tid>>1, 32-col half)
    const int trow = tid >> 1;
    const int tc = (tid & 1) * 32;
    const float* tp = x + (size_t)toks[trow] * H_DIM + tc;

    f32x4 acc[8];
    #pragma unroll
    for (int j = 0; j < 8; ++j) acc[j] = (f32x4){0.f, 0.f, 0.f, 0.f};

    float4 pw0, pw1, pw2, pw3;   // weight prefetch (slice k, consumed at iter k)
    float4 tf[8];                // token prefetch (tile k+1 at top of iter k)

    // ---- prologue ----
    // tokens tile 0 -> Bs[0]
    #pragma unroll
    for (int j = 0; j < 8; ++j) tf[j] = *(const float4*)(tp + j * 4);
    #pragma unroll
    for (int c = 0; c < 4; ++c)
        *(uint4*)&Bs[0][trow * AP + tc + c * 8] = pkq(tf[2*c], tf[2*c+1]);
    // weights slice 0
    pw0 = *(const float4*)(wp + 0);
    pw1 = *(const float4*)(wp + 4);
    pw2 = *(const float4*)(wp + 32);
    pw3 = *(const float4*)(wp + 36);
    // tokens tile 1
    #pragma unroll
    for (int j = 0; j < 8; ++j) tf[j] = *(const float4*)(tp + 64 + j * 4);
    wave_barrier();

    int buf = 0;
    for (int k = 0; k < NK; ++k) {
        const int kn = (k + 1) * 64;
        // weights k -> frags (vmcnt wait covered: loaded a full iter ago)
        bf16x8 af0 = cvt8(pw0, pw1);
        bf16x8 af1 = cvt8(pw2, pw3);
        // tokens tile k+1 (loaded a full iter ago) -> other LDS buffer
        if (k + 1 < NK) {
            #pragma unroll
            for (int c = 0; c < 4; ++c)
                *(uint4*)&Bs[buf ^ 1][trow * AP + tc + c * 8] = pkq(tf[2*c], tf[2*c+1]);
            // issue weights k+1
            pw0 = *(const float4*)(wp + kn);
            pw1 = *(const float4*)(wp + kn + 4);
            pw2 = *(const float4*)(wp + kn + 32);
            pw3 = *(const float4*)(wp + kn + 36);
        }
        // issue tokens tile k+2
        if (k + 2 < NK) {
            #pragma unroll
            for (int j = 0; j < 8; ++j) tf[j] = *(const float4*)(tp + kn + 64 + j * 4);
        }
        // MFMA cluster on Bs[buf]
        #pragma unroll
        for (int ks = 0; ks < 2; ++ks) {
            bf16x8 a = ks ? af1 : af0;
            #pragma unroll
            for (int nj = 0; nj < 8; ++nj) {
                bf16x8 b = *(const bf16x8*)&Bs[buf][(nj * 16 + lr) * AP + ks * 32 + lq * 8];
                acc[nj] = __builtin_amdgcn_mfma_f32_16x16x32_bf16(a, b, acc[nj], 0, 0, 0);
            }
        }
        wave_barrier();   // publishes Bs[buf^1]; global loads stay in flight
        buf ^= 1;
    }

    // ---- epilogue: gate waves hand acc to up waves via LDS (aliased over Bs) ----
    float* gex = (float*)&Bs[0][0];   // 16 KB <= 36 KB
    if (!isup) {
        #pragma unroll
        for (int nj = 0; nj < 8; ++nj)
            *(f32x4*)&gex[((rhalf * 8 + nj) * 64 + lane) * 4] = acc[nj];
    }
    __syncthreads();
    if (isup) {
        #pragma unroll
        for (int nj = 0; nj < 8; ++nj) {
            int sl = nj * 16 + lr;                 // slot within tile (D col = lane&15)
            f32x4 g = *(const f32x4*)&gex[((rhalf * 8 + nj) * 64 + lane) * 4];
            float w = wts[sl];
            unsigned short o[4];
            #pragma unroll
            for (int r = 0; r < 4; ++r) {
                float gg = g[r];
                float a = w * (gg / (1.f + __expf(-gg))) * acc[nj][r];
                o[r] = bf1(a);
            }
            if (s0 + sl < cnt) {
                // blocked layout: 4 consecutive I-cols of this slot's 32-col chunk -> 8 B store
                uint2 pkd = make_uint2((unsigned)o[0] | ((unsigned)o[1] << 16),
                                       (unsigned)o[2] | ((unsigned)o[3] << 16));
                *(uint2*)(act + ABLK(blockIdx.x, off + s0 + sl) + rhalf * 16 + lq * 4) = pkd;
            }
        }
    }
}

// ---------------- routed down proj: Wd global->reg, act LDS dbuf, 2-deep pipeline ----------------
// D[m = H-row][n = slot].  Block: 64 H-rows x 128 slots, wave wv owns rows wv*16..+16.
// Reads act in blocked layout; writes slot_out in blocked layout (contiguous, no RMW).
__global__ __launch_bounds__(256, 4) void down_routed_mfma(
    const unsigned short* __restrict__ act, const float* __restrict__ Wd,
    const int* __restrict__ offs, const int* __restrict__ counts,
    float* __restrict__ slot_out)
{
    const int e = blockIdx.z;
    const int cnt = counts[e];
    const int s0 = blockIdx.y * 128;
    if (s0 >= cnt) return;
    const int off = offs[e];
    const int h0 = blockIdx.x * 64;
    const int NK = I_DIM / 64;   // 11

    __shared__ unsigned short Bs[2][128 * AP];   // act tile, double-buffered

    const int tid = threadIdx.x;
    const int lane = tid & 63;
    const int wv = tid >> 6;
    const int lr = lane & 15;
    const int lq = lane >> 4;

    const float* wp = Wd + (size_t)e * H_DIM * I_DIM
                    + (size_t)(h0 + wv * 16 + lr) * I_DIM + lq * 8;

    // act staging: thread -> (slot row = tid>>1, 32-col half)
    int srow = s0 + (tid >> 1);
    if (srow > cnt - 1) srow = cnt - 1;          // clamp: pad rows masked at store
    const int sc_half = tid & 1;
    const size_t arow = (size_t)(off + srow);

    f32x4 acc[8];
    #pragma unroll
    for (int j = 0; j < 8; ++j) acc[j] = (f32x4){0.f, 0.f, 0.f, 0.f};

    float4 pw0, pw1, pw2, pw3;
    uint4 tf[4];   // 64 B of bf16 act per thread

    // ---- prologue ----
    #pragma unroll
    for (int j = 0; j < 4; ++j) tf[j] = *(const uint4*)(act + ABLK(sc_half, arow) + j * 8);
    #pragma unroll
    for (int j = 0; j < 4; ++j)
        *(uint4*)&Bs[0][(tid >> 1) * AP + sc_half * 32 + j * 8] = tf[j];
    pw0 = *(const float4*)(wp + 0);
    pw1 = *(const float4*)(wp + 4);
    pw2 = *(const float4*)(wp + 32);
    pw3 = *(const float4*)(wp + 36);
    #pragma unroll
    for (int j = 0; j < 4; ++j) tf[j] = *(const uint4*)(act + ABLK(2 + sc_half, arow) + j * 8);
    wave_barrier();

    int buf = 0;
    for (int k = 0; k < NK; ++k) {
        const int kn = (k + 1) * 64;
        bf16x8 af0 = cvt8(pw0, pw1);
        bf16x8 af1 = cvt8(pw2, pw3);
        if (k + 1 < NK) {
            #pragma unroll
            for (int j = 0; j < 4; ++j)
                *(uint4*)&Bs[buf ^ 1][(tid >> 1) * AP + sc_half * 32 + j * 8] = tf[j];
            pw0 = *(const float4*)(wp + kn);
            pw1 = *(const float4*)(wp + kn + 4);
            pw2 = *(const float4*)(wp + kn + 32);
            pw3 = *(const float4*)(wp + kn + 36);
        }
        if (k + 2 < NK) {
            #pragma unroll
            for (int j = 0; j < 4; ++j)
                tf[j] = *(const uint4*)(act + ABLK((k + 2) * 2 + sc_half, arow) + j * 8);
        }
        #pragma unroll
        for (int ks = 0; ks < 2; ++ks) {
            bf16x8 a = ks ? af1 : af0;
            #pragma unroll
            for (int nj = 0; nj < 8; ++nj) {
                bf16x8 b = *(const bf16x8*)&Bs[buf][(nj * 16 + lr) * AP + ks * 32 + lq * 8];
                acc[nj] = __builtin_amdgcn_mfma_f32_16x16x32_bf16(a, b, acc[nj], 0, 0, 0);
            }
        }
        wave_barrier();
        buf ^= 1;
    }

    // store: blocked layout, 16 B contiguous per lane, 64 B per slot chunk
    #pragma unroll
    for (int nj = 0; nj < 8; ++nj) {
        int sl = nj * 16 + lr;
        if (s0 + sl < cnt)
            *(f32x4*)(slot_out + SBLK(blockIdx.x, off + s0 + sl) + wv * 16 + lq * 4) = acc[nj];
    }
}

// ---------------- combine: out[t] += sum_k slot_blk[h-tile][pos(t,k)][h%64] ----------------
__global__ __launch_bounds__(256) void combine_kernel(
    const float* __restrict__ slot_out, const int* __restrict__ tk_pos,
    float* __restrict__ out)
{
    const int t = blockIdx.x;
    __shared__ int pos[TOPK];
    if (threadIdx.x < TOPK) pos[threadIdx.x] = tk_pos[t * TOPK + threadIdx.x];
    __syncthreads();
    const int i = threadIdx.x;     // h = 4i .. 4i+3
    const int ht = i >> 4;         // h-tile of 64
    const int hc = (i & 15) * 4;   // col within tile
    float4 a = ((const float4*)(out + (size_t)t * H_DIM))[i];
    #pragma unroll
    for (int k = 0; k < TOPK; ++k) {
        float4 v = *(const float4*)(slot_out + SBLK(ht, pos[k]) + hc);
        a.x += v.x; a.y += v.y; a.z += v.z; a.w += v.w;
    }
    ((float4*)(out + (size_t)t * H_DIM))[i] = a;
}

// ---------------- shared expert gate/up: MFMA dense (round-0 proven body) ----------------
__global__ __launch_bounds__(256) void gateup_shared_mfma(
    const float* __restrict__ x, const float* __restrict__ Sg, const float* __restrict__ Su,
    unsigned short* __restrict__ sact)
{
    const int m0 = blockIdx.y * 128;
    const int n0 = blockIdx.x * 64;

    __shared__ unsigned short As[128 * AP];
    __shared__ unsigned short Bg[64 * AP];
    __shared__ unsigned short Bu[64 * AP];

    const int tid = threadIdx.x;
    const int lane = tid & 63;
    const int wv = tid >> 6;
    const int lr = lane & 15;
    const int lq = lane >> 4;

    f32x4 accg[2][4], accu[2][4];
    #pragma unroll
    for (int i = 0; i < 2; ++i)
        #pragma unroll
        for (int j = 0; j < 4; ++j) {
            accg[i][j] = (f32x4){0.f, 0.f, 0.f, 0.f};
            accu[i][j] = (f32x4){0.f, 0.f, 0.f, 0.f};
        }

    const float* gp = Sg + (size_t)n0 * H_DIM;
    const float* up = Su + (size_t)n0 * H_DIM;
    const int ar = tid >> 4;
    const int ac = (tid & 15) * 4;

    for (int k0 = 0; k0 < H_DIM; k0 += 64) {
        #pragma unroll
        for (int p = 0; p < 8; ++p) {
            int r = ar + p * 16;
            float4 v = *(const float4*)(x + (size_t)(m0 + r) * H_DIM + k0 + ac);
            *(uint2*)&As[r * AP + ac] = make_uint2(pk2(v.x, v.y), pk2(v.z, v.w));
        }
        #pragma unroll
        for (int p = 0; p < 4; ++p) {
            int r = ar + p * 16;
            float4 g = *(const float4*)(gp + (size_t)r * H_DIM + k0 + ac);
            *(uint2*)&Bg[r * AP + ac] = make_uint2(pk2(g.x, g.y), pk2(g.z, g.w));
            float4 u = *(const float4*)(up + (size_t)r * H_DIM + k0 + ac);
            *(uint2*)&Bu[r * AP + ac] = make_uint2(pk2(u.x, u.y), pk2(u.z, u.w));
        }
        __syncthreads();
        #pragma unroll
        for (int ks = 0; ks < 2; ++ks) {
            bf16x8 a0 = *(const bf16x8*)&As[(wv * 32 + lr) * AP + ks * 32 + lq * 8];
            bf16x8 a1 = *(const bf16x8*)&As[(wv * 32 + 16 + lr) * AP + ks * 32 + lq * 8];
            #pragma unroll
            for (int nj = 0; nj < 4; ++nj) {
                bf16x8 bg = *(const bf16x8*)&Bg[(nj * 16 + lr) * AP + ks * 32 + lq * 8];
                bf16x8 bu = *(const bf16x8*)&Bu[(nj * 16 + lr) * AP + ks * 32 + lq * 8];
                accg[0][nj] = __builtin_amdgcn_mfma_f32_16x16x32_bf16(a0, bg, accg[0][nj], 0, 0, 0);
                accg[1][nj] = __builtin_amdgcn_mfma_f32_16x16x32_bf16(a1, bg, accg[1][nj], 0, 0, 0);
                accu[0][nj] = __builtin_amdgcn_mfma_f32_16x16x32_bf16(a0, bu, accu[0][nj], 0, 0, 0);
                accu[1][nj] = __builtin_amdgcn_mfma_f32_16x16x32_bf16(a1, bu, accu[1][nj], 0, 0, 0);
            }
        }
        __syncthreads();
    }

    #pragma unroll
    for (int mi = 0; mi < 2; ++mi) {
        #pragma unroll
        for (int r = 0; r < 4; ++r) {
            int trow = m0 + wv * 32 + mi * 16 + lq * 4 + r;
            unsigned short* sp = sact + (size_t)trow * SI_DIM + n0 + lr;
            #pragma unroll
            for (int nj = 0; nj < 4; ++nj) {
                float g = accg[mi][nj][r];
                float u = accu[mi][nj][r];
                float a = (g / (1.f + __expf(-g))) * u;
                sp[nj * 16] = bf1(a);
            }
        }
    }
}

// ---------------- shared expert down proj: MFMA dense (round-0 proven body) ----------------
__global__ __launch_bounds__(256) void down_shared_mfma(
    const unsigned short* __restrict__ sact, const float* __restrict__ Sd,
    float* __restrict__ out)
{
    const int m0 = blockIdx.y * 128;
    const int n0 = blockIdx.x * 64;

    __shared__ unsigned short As[128 * AP];
    __shared__ unsigned short Bs[64 * AP];

    const int tid = threadIdx.x;
    const int lane = tid & 63;
    const int wv = tid >> 6;
    const int lr = lane & 15;
    const int lq = lane >> 4;

    f32x4 acc[2][4];
    #pragma unroll
    for (int i = 0; i < 2; ++i)
        #pragma unroll
        for (int j = 0; j < 4; ++j)
            acc[i][j] = (f32x4){0.f, 0.f, 0.f, 0.f};

    const float* wp = Sd + (size_t)n0 * SI_DIM;
    const int ar = tid >> 4;
    const int ac = (tid & 15) * 4;

    for (int k0 = 0; k0 < SI_DIM; k0 += 64) {
        #pragma unroll
        for (int p = 0; p < 8; ++p) {
            int r = ar + p * 16;
            uint2 v = *(const uint2*)(sact + (size_t)(m0 + r) * SI_DIM + k0 + ac);
            *(uint2*)&As[r * AP + ac] = v;
        }
        #pragma unroll
        for (int p = 0; p < 4; ++p) {
            int r = ar + p * 16;
            float4 w4 = *(const float4*)(wp + (size_t)r * SI_DIM + k0 + ac);
            *(uint2*)&Bs[r * AP + ac] = make_uint2(pk2(w4.x, w4.y), pk2(w4.z, w4.w));
        }
        __syncthreads();
        #pragma unroll
        for (int ks = 0; ks < 2; ++ks) {
            bf16x8 a0 = *(const bf16x8*)&As[(wv * 32 + lr) * AP + ks * 32 + lq * 8];
            bf16x8 a1 = *(const bf16x8*)&As[(wv * 32 + 16 + lr) * AP + ks * 32 + lq * 8];
            #pragma unroll
            for (int nj = 0; nj < 4; ++nj) {
                bf16x8 b = *(const bf16x8*)&Bs[(nj * 16 + lr) * AP + ks * 32 + lq * 8];
                acc[0][nj] = __builtin_amdgcn_mfma_f32_16x16x32_bf16(a0, b, acc[0][nj], 0, 0, 0);
                acc[1][nj] = __builtin_amdgcn_mfma_f32_16x16x32_bf16(a1, b, acc[1][nj], 0, 0, 0);
            }
        }
        __syncthreads();
    }

    #pragma unroll
    for (int mi = 0; mi < 2; ++mi) {
        #pragma unroll
        for (int r = 0; r < 4; ++r) {
            int trow = m0 + wv * 32 + mi * 16 + lq * 4 + r;
            float* op = out + (size_t)trow * H_DIM + n0 + lr;
            #pragma unroll
            for (int nj = 0; nj < 4; ++nj)
                op[nj * 16] = acc[mi][nj][r];
        }
    }
}

// ---------------- launch ----------------
extern "C" void kernel_launch(void* const* d_in, const int* in_sizes, int n_in,
                              void* d_out, int out_size, void* d_ws, size_t ws_size,
                              hipStream_t stream)
{
    const float* x  = (const float*)d_in[0];
    const float* gw = (const float*)d_in[1];
    const float* gb = (const float*)d_in[2];
    const float* Wg = (const float*)d_in[3];
    const float* Wu = (const float*)d_in[4];
    const float* Wd = (const float*)d_in[5];
    const float* Sg = (const float*)d_in[6];
    const float* Su = (const float*)d_in[7];
    const float* Sd = (const float*)d_in[8];
    float* out = (float*)d_out;

    // workspace layout (16B-aligned chunks first)
    float* slot_out = (float*)d_ws;                                   // 16*NSLOT*64 f32 = 33.5 MB (blocked)
    unsigned short* act  = (unsigned short*)(slot_out + (size_t)NSLOT * H_DIM);  // 22*NSLOT*32 bf16 (blocked)
    unsigned short* sact = act + (size_t)NSLOT * I_DIM;               // 1024*1408 bf16
    int* counts   = (int*)(sact + (size_t)T_TOK * SI_DIM);            // 64
    int* fillc    = counts + 64;                                      // 64
    int* offs     = fillc + 64;                                       // 64
    int* tk_idx   = offs + 64;                                        // 8192
    float* tk_w   = (float*)(tk_idx + NSLOT);                         // 8192
    int* tok_list = (int*)(tk_w + NSLOT);                             // 8192
    float* w_list = (float*)(tok_list + NSLOT);                       // 8192
    int* tk_pos   = (int*)(w_list + NSLOT);                           // 8192

    zero_kernel<<<1, 64, 0, stream>>>(counts, fillc);
    route_kernel<<<T_TOK, 64, 0, stream>>>(x, gw, gb, counts, tk_idx, tk_w);
    scan_kernel<<<1, 64, 0, stream>>>(counts, offs);
    fill_kernel<<<4, 256, 0, stream>>>(tk_idx, tk_w, offs, fillc, tok_list, w_list, tk_pos);

    gateup_routed_mfma<<<dim3(22, 8, 64), 256, 0, stream>>>(x, Wg, Wu, offs, counts, tok_list, w_list, act);
    gateup_shared_mfma<<<dim3(22, 8, 1), 256, 0, stream>>>(x, Sg, Su, sact);
    down_shared_mfma<<<dim3(16, 8, 1), 256, 0, stream>>>(sact, Sd, out);
    down_routed_mfma<<<dim3(16, 8, 64), 256, 0, stream>>>(act, Wd, offs, counts, slot_out);
    combine_kernel<<<T_TOK, 256, 0, stream>>>(slot_out, tk_pos, out);
}

// Round 5
// 808.163 us; speedup vs baseline: 1.2326x; 1.1651x over previous
//
#include <hip/hip_runtime.h>
#include <hip/hip_bf16.h>
#include <cstdint>
#include <cstddef>

// ---- problem constants (DeepSeek-V3 MoE config) ----
#define T_TOK 1024
#define H_DIM 1024
#define I_DIM 704
#define E_NUM 64
#define TOPK 8
#define NGRP 8
#define GSIZE 8          // E_NUM / NGRP
#define TOPKG 4
#define SI_DIM 1408
#define RSCALE 2.5f
#define NSLOT (T_TOK * TOPK)   // 8192
#define MAXBLK 128             // max live (expert, slot-tile) blocks: sum ceil(cnt/128) <= 128

#define AP 72            // LDS row pitch in bf16 elems (144 B rows, 2-way max bank aliasing)

typedef short bf16x8 __attribute__((ext_vector_type(8)));
typedef float f32x4 __attribute__((ext_vector_type(4)));

__device__ inline unsigned pk2(float x, float y) {
    __hip_bfloat162 h2 = __float22bfloat162_rn(make_float2(x, y));
    unsigned u; __builtin_memcpy(&u, &h2, 4); return u;
}
__device__ inline unsigned short bf1(float x) {
    __hip_bfloat16 h = __float2bfloat16(x);
    unsigned short u; __builtin_memcpy(&u, &h, 2); return u;
}

// ---------------- routing ----------------
__global__ __launch_bounds__(64) void route_kernel(
    const float* __restrict__ x, const float* __restrict__ gw, const float* __restrict__ gb,
    int* __restrict__ counts, int* __restrict__ tk_idx, float* __restrict__ tk_w)
{
    const int t = blockIdx.x;
    __shared__ float xs[H_DIM];
    __shared__ float raw[E_NUM];
    __shared__ float sc[E_NUM];
    __shared__ float masked[E_NUM];
    __shared__ float gsc[NGRP];
    const int tid = threadIdx.x;

    const float4* xrow = (const float4*)(x + (size_t)t * H_DIM);
    for (int i = tid; i < H_DIM / 4; i += 64) ((float4*)xs)[i] = xrow[i];
    __syncthreads();

    float a = 0.f;
    const float* w = gw + (size_t)tid * H_DIM;
    for (int h = 0; h < H_DIM; h += 4) {
        float4 w4 = *(const float4*)(w + h);
        a += xs[h] * w4.x + xs[h+1] * w4.y + xs[h+2] * w4.z + xs[h+3] * w4.w;
    }
    float s = 1.f / (1.f + expf(-a));
    raw[tid] = s;
    sc[tid] = s + gb[tid];
    __syncthreads();

    if (tid == 0) {
        for (int g = 0; g < NGRP; ++g) {
            float m1 = -1e30f, m2 = -1e30f;
            for (int j = 0; j < GSIZE; ++j) {
                float v = sc[g * GSIZE + j];
                if (v > m1) { m2 = m1; m1 = v; }
                else if (v > m2) { m2 = v; }
            }
            gsc[g] = m1 + m2;
        }
        bool gsel[NGRP];
        for (int g = 0; g < NGRP; ++g) gsel[g] = false;
        for (int k = 0; k < TOPKG; ++k) {
            int best = -1; float bv = -1e30f;
            for (int g = 0; g < NGRP; ++g)
                if (!gsel[g] && gsc[g] > bv) { bv = gsc[g]; best = g; }
            gsel[best] = true;
        }
        for (int e = 0; e < E_NUM; ++e)
            masked[e] = gsel[e / GSIZE] ? sc[e] : 0.0f;
        int idx[TOPK];
        float wsum = 0.f;
        for (int k = 0; k < TOPK; ++k) {
            int best = 0; float bv = -1e30f;
            for (int e = 0; e < E_NUM; ++e)
                if (masked[e] > bv) { bv = masked[e]; best = e; }
            masked[best] = -1e30f;
            idx[k] = best;
            wsum += raw[best];
        }
        float inv = RSCALE / (wsum + 1e-20f);
        for (int k = 0; k < TOPK; ++k) {
            tk_idx[t * TOPK + k] = idx[k];
            tk_w[t * TOPK + k] = raw[idx[k]] * inv;
            atomicAdd(&counts[idx[k]], 1);
        }
    }
}

__global__ void zero_kernel(int* counts, int* fillc)
{
    int i = threadIdx.x;
    if (i < E_NUM) { counts[i] = 0; fillc[i] = 0; }
}

// scan + build dense live-block list: grid front becomes 100% live work
__global__ void scan_kernel(const int* __restrict__ counts, int* __restrict__ offs,
                            int* __restrict__ blk_e, int* __restrict__ blk_s0,
                            int* __restrict__ nblk)
{
    if (threadIdx.x == 0) {
        int acc = 0;
        for (int e = 0; e < E_NUM; ++e) { offs[e] = acc; acc += counts[e]; }
        int n = 0;
        for (int e = 0; e < E_NUM; ++e)
            for (int t = 0; t < counts[e]; t += 128) { blk_e[n] = e; blk_s0[n] = t; ++n; }
        nblk[0] = n;
    }
}

__global__ void fill_kernel(const int* __restrict__ tk_idx, const float* __restrict__ tk_w,
                            const int* __restrict__ offs, int* __restrict__ fillc,
                            int* __restrict__ tok_list, float* __restrict__ w_list,
                            int* __restrict__ tk_pos)
{
    int t = blockIdx.x * blockDim.x + threadIdx.x;
    if (t >= T_TOK) return;
    for (int k = 0; k < TOPK; ++k) {
        int e = tk_idx[t * TOPK + k];
        int pos = offs[e] + atomicAdd(&fillc[e], 1);
        tok_list[pos] = t;
        w_list[pos] = tk_w[t * TOPK + k];
        tk_pos[t * TOPK + k] = pos;
    }
}

// ---------------- routed gate/up: round-0 proven body, flattened live-block grid ----------------
__global__ __launch_bounds__(256) void gateup_routed_mfma(
    const float* __restrict__ x, const float* __restrict__ Wg, const float* __restrict__ Wu,
    const int* __restrict__ offs, const int* __restrict__ counts,
    const int* __restrict__ tok_list, const float* __restrict__ w_list,
    const int* __restrict__ blk_e, const int* __restrict__ blk_s0, const int* __restrict__ nblk,
    unsigned short* __restrict__ act)
{
    const int by = blockIdx.y;
    if (by >= nblk[0]) return;          // trailing dead blocks only — dispatch front is dense
    const int e = blk_e[by];
    const int m0 = blk_s0[by];
    const int cnt = counts[e];
    const int off = offs[e];
    const int n0 = blockIdx.x * 64;

    __shared__ unsigned short As[128 * AP];
    __shared__ unsigned short Bg[64 * AP];
    __shared__ unsigned short Bu[64 * AP];
    __shared__ int toks[128];
    __shared__ float wts[128];

    const int tid = threadIdx.x;
    if (tid < 128) {
        int s = m0 + tid;
        toks[tid] = (s < cnt) ? tok_list[off + s] : -1;
        wts[tid]  = (s < cnt) ? w_list[off + s] : 0.f;
    }
    __syncthreads();

    const int lane = tid & 63;
    const int wv = tid >> 6;
    const int lr = lane & 15;
    const int lq = lane >> 4;

    f32x4 accg[2][4], accu[2][4];
    #pragma unroll
    for (int i = 0; i < 2; ++i)
        #pragma unroll
        for (int j = 0; j < 4; ++j) {
            accg[i][j] = (f32x4){0.f, 0.f, 0.f, 0.f};
            accu[i][j] = (f32x4){0.f, 0.f, 0.f, 0.f};
        }

    const float* wgp = Wg + (size_t)e * I_DIM * H_DIM + (size_t)n0 * H_DIM;
    const float* wup = Wu + (size_t)e * I_DIM * H_DIM + (size_t)n0 * H_DIM;

    const int ar = tid >> 4;          // 0..15
    const int ac = (tid & 15) * 4;    // 0..60

    for (int k0 = 0; k0 < H_DIM; k0 += 64) {
        #pragma unroll
        for (int p = 0; p < 8; ++p) {
            int r = ar + p * 16;
            int tkn = toks[r];
            float4 v = make_float4(0.f, 0.f, 0.f, 0.f);
            if (tkn >= 0) v = *(const float4*)(x + (size_t)tkn * H_DIM + k0 + ac);
            *(uint2*)&As[r * AP + ac] = make_uint2(pk2(v.x, v.y), pk2(v.z, v.w));
        }
        #pragma unroll
        for (int p = 0; p < 4; ++p) {
            int r = ar + p * 16;
            float4 g = *(const float4*)(wgp + (size_t)r * H_DIM + k0 + ac);
            *(uint2*)&Bg[r * AP + ac] = make_uint2(pk2(g.x, g.y), pk2(g.z, g.w));
            float4 u = *(const float4*)(wup + (size_t)r * H_DIM + k0 + ac);
            *(uint2*)&Bu[r * AP + ac] = make_uint2(pk2(u.x, u.y), pk2(u.z, u.w));
        }
        __syncthreads();
        #pragma unroll
        for (int ks = 0; ks < 2; ++ks) {
            bf16x8 a0 = *(const bf16x8*)&As[(wv * 32 + lr) * AP + ks * 32 + lq * 8];
            bf16x8 a1 = *(const bf16x8*)&As[(wv * 32 + 16 + lr) * AP + ks * 32 + lq * 8];
            #pragma unroll
            for (int nj = 0; nj < 4; ++nj) {
                bf16x8 bg = *(const bf16x8*)&Bg[(nj * 16 + lr) * AP + ks * 32 + lq * 8];
                bf16x8 bu = *(const bf16x8*)&Bu[(nj * 16 + lr) * AP + ks * 32 + lq * 8];
                accg[0][nj] = __builtin_amdgcn_mfma_f32_16x16x32_bf16(a0, bg, accg[0][nj], 0, 0, 0);
                accg[1][nj] = __builtin_amdgcn_mfma_f32_16x16x32_bf16(a1, bg, accg[1][nj], 0, 0, 0);
                accu[0][nj] = __builtin_amdgcn_mfma_f32_16x16x32_bf16(a0, bu, accu[0][nj], 0, 0, 0);
                accu[1][nj] = __builtin_amdgcn_mfma_f32_16x16x32_bf16(a1, bu, accu[1][nj], 0, 0, 0);
            }
        }
        __syncthreads();
    }

    #pragma unroll
    for (int mi = 0; mi < 2; ++mi) {
        #pragma unroll
        for (int r = 0; r < 4; ++r) {
            int srow = wv * 32 + mi * 16 + lq * 4 + r;
            if (m0 + srow < cnt) {
                float w = wts[srow];
                unsigned short* ap = act + (size_t)(off + m0 + srow) * I_DIM + n0 + lr;
                #pragma unroll
                for (int nj = 0; nj < 4; ++nj) {
                    float g = accg[mi][nj][r];
                    float u = accu[mi][nj][r];
                    float a = w * (g / (1.f + __expf(-g))) * u;
                    ap[nj * 16] = bf1(a);
                }
            }
        }
    }
}

// ---------------- routed down proj: round-0 proven body, flattened grid, slot_out stores ----------------
__global__ __launch_bounds__(256) void down_routed_mfma(
    const unsigned short* __restrict__ act, const float* __restrict__ Wd,
    const int* __restrict__ offs, const int* __restrict__ counts,
    const int* __restrict__ blk_e, const int* __restrict__ blk_s0, const int* __restrict__ nblk,
    float* __restrict__ slot_out)
{
    const int by = blockIdx.y;
    if (by >= nblk[0]) return;
    const int e = blk_e[by];
    const int m0 = blk_s0[by];
    const int cnt = counts[e];
    const int off = offs[e];
    const int n0 = blockIdx.x * 64;

    __shared__ unsigned short As[128 * AP];
    __shared__ unsigned short Bs[64 * AP];

    const int tid = threadIdx.x;
    const int lane = tid & 63;
    const int wv = tid >> 6;
    const int lr = lane & 15;
    const int lq = lane >> 4;

    f32x4 acc[2][4];
    #pragma unroll
    for (int i = 0; i < 2; ++i)
        #pragma unroll
        for (int j = 0; j < 4; ++j)
            acc[i][j] = (f32x4){0.f, 0.f, 0.f, 0.f};

    const float* wdp = Wd + (size_t)e * H_DIM * I_DIM + (size_t)n0 * I_DIM;
    const unsigned short* ap0 = act + (size_t)(off + m0) * I_DIM;
    const int ar = tid >> 4;
    const int ac = (tid & 15) * 4;

    for (int k0 = 0; k0 < I_DIM; k0 += 64) {
        #pragma unroll
        for (int p = 0; p < 8; ++p) {
            int r = ar + p * 16;
            uint2 v = make_uint2(0u, 0u);
            if (m0 + r < cnt) v = *(const uint2*)(ap0 + (size_t)r * I_DIM + k0 + ac);
            *(uint2*)&As[r * AP + ac] = v;
        }
        #pragma unroll
        for (int p = 0; p < 4; ++p) {
            int r = ar + p * 16;
            float4 w4 = *(const float4*)(wdp + (size_t)r * I_DIM + k0 + ac);
            *(uint2*)&Bs[r * AP + ac] = make_uint2(pk2(w4.x, w4.y), pk2(w4.z, w4.w));
        }
        __syncthreads();
        #pragma unroll
        for (int ks = 0; ks < 2; ++ks) {
            bf16x8 a0 = *(const bf16x8*)&As[(wv * 32 + lr) * AP + ks * 32 + lq * 8];
            bf16x8 a1 = *(const bf16x8*)&As[(wv * 32 + 16 + lr) * AP + ks * 32 + lq * 8];
            #pragma unroll
            for (int nj = 0; nj < 4; ++nj) {
                bf16x8 b = *(const bf16x8*)&Bs[(nj * 16 + lr) * AP + ks * 32 + lq * 8];
                acc[0][nj] = __builtin_amdgcn_mfma_f32_16x16x32_bf16(a0, b, acc[0][nj], 0, 0, 0);
                acc[1][nj] = __builtin_amdgcn_mfma_f32_16x16x32_bf16(a1, b, acc[1][nj], 0, 0, 0);
            }
        }
        __syncthreads();
    }

    #pragma unroll
    for (int mi = 0; mi < 2; ++mi) {
        #pragma unroll
        for (int r = 0; r < 4; ++r) {
            int srow = wv * 32 + mi * 16 + lq * 4 + r;
            if (m0 + srow < cnt) {
                float* op = slot_out + (size_t)(off + m0 + srow) * H_DIM + n0 + lr;
                #pragma unroll
                for (int nj = 0; nj < 4; ++nj)
                    op[nj * 16] = acc[mi][nj][r];
            }
        }
    }
}

// ---------------- combine: out[t] += sum_k slot_out[pos(t,k)] ----------------
__global__ __launch_bounds__(256) void combine_kernel(
    const float* __restrict__ slot_out, const int* __restrict__ tk_pos,
    float* __restrict__ out)
{
    const int t = blockIdx.x;
    __shared__ int pos[TOPK];
    if (threadIdx.x < TOPK) pos[threadIdx.x] = tk_pos[t * TOPK + threadIdx.x];
    __syncthreads();
    const int i = threadIdx.x;   // 256 threads x float4 = 1024 floats
    float4 a = ((const float4*)(out + (size_t)t * H_DIM))[i];
    #pragma unroll
    for (int k = 0; k < TOPK; ++k) {
        float4 v = ((const float4*)(slot_out + (size_t)pos[k] * H_DIM))[i];
        a.x += v.x; a.y += v.y; a.z += v.z; a.w += v.w;
    }
    ((float4*)(out + (size_t)t * H_DIM))[i] = a;
}

// ---------------- shared expert gate/up: MFMA dense (round-0 proven body) ----------------
__global__ __launch_bounds__(256) void gateup_shared_mfma(
    const float* __restrict__ x, const float* __restrict__ Sg, const float* __restrict__ Su,
    unsigned short* __restrict__ sact)
{
    const int m0 = blockIdx.y * 128;
    const int n0 = blockIdx.x * 64;

    __shared__ unsigned short As[128 * AP];
    __shared__ unsigned short Bg[64 * AP];
    __shared__ unsigned short Bu[64 * AP];

    const int tid = threadIdx.x;
    const int lane = tid & 63;
    const int wv = tid >> 6;
    const int lr = lane & 15;
    const int lq = lane >> 4;

    f32x4 accg[2][4], accu[2][4];
    #pragma unroll
    for (int i = 0; i < 2; ++i)
        #pragma unroll
        for (int j = 0; j < 4; ++j) {
            accg[i][j] = (f32x4){0.f, 0.f, 0.f, 0.f};
            accu[i][j] = (f32x4){0.f, 0.f, 0.f, 0.f};
        }

    const float* gp = Sg + (size_t)n0 * H_DIM;
    const float* up = Su + (size_t)n0 * H_DIM;
    const int ar = tid >> 4;
    const int ac = (tid & 15) * 4;

    for (int k0 = 0; k0 < H_DIM; k0 += 64) {
        #pragma unroll
        for (int p = 0; p < 8; ++p) {
            int r = ar + p * 16;
            float4 v = *(const float4*)(x + (size_t)(m0 + r) * H_DIM + k0 + ac);
            *(uint2*)&As[r * AP + ac] = make_uint2(pk2(v.x, v.y), pk2(v.z, v.w));
        }
        #pragma unroll
        for (int p = 0; p < 4; ++p) {
            int r = ar + p * 16;
            float4 g = *(const float4*)(gp + (size_t)r * H_DIM + k0 + ac);
            *(uint2*)&Bg[r * AP + ac] = make_uint2(pk2(g.x, g.y), pk2(g.z, g.w));
            float4 u = *(const float4*)(up + (size_t)r * H_DIM + k0 + ac);
            *(uint2*)&Bu[r * AP + ac] = make_uint2(pk2(u.x, u.y), pk2(u.z, u.w));
        }
        __syncthreads();
        #pragma unroll
        for (int ks = 0; ks < 2; ++ks) {
            bf16x8 a0 = *(const bf16x8*)&As[(wv * 32 + lr) * AP + ks * 32 + lq * 8];
            bf16x8 a1 = *(const bf16x8*)&As[(wv * 32 + 16 + lr) * AP + ks * 32 + lq * 8];
            #pragma unroll
            for (int nj = 0; nj < 4; ++nj) {
                bf16x8 bg = *(const bf16x8*)&Bg[(nj * 16 + lr) * AP + ks * 32 + lq * 8];
                bf16x8 bu = *(const bf16x8*)&Bu[(nj * 16 + lr) * AP + ks * 32 + lq * 8];
                accg[0][nj] = __builtin_amdgcn_mfma_f32_16x16x32_bf16(a0, bg, accg[0][nj], 0, 0, 0);
                accg[1][nj] = __builtin_amdgcn_mfma_f32_16x16x32_bf16(a1, bg, accg[1][nj], 0, 0, 0);
                accu[0][nj] = __builtin_amdgcn_mfma_f32_16x16x32_bf16(a0, bu, accu[0][nj], 0, 0, 0);
                accu[1][nj] = __builtin_amdgcn_mfma_f32_16x16x32_bf16(a1, bu, accu[1][nj], 0, 0, 0);
            }
        }
        __syncthreads();
    }

    #pragma unroll
    for (int mi = 0; mi < 2; ++mi) {
        #pragma unroll
        for (int r = 0; r < 4; ++r) {
            int trow = m0 + wv * 32 + mi * 16 + lq * 4 + r;
            unsigned short* sp = sact + (size_t)trow * SI_DIM + n0 + lr;
            #pragma unroll
            for (int nj = 0; nj < 4; ++nj) {
                float g = accg[mi][nj][r];
                float u = accu[mi][nj][r];
                float a = (g / (1.f + __expf(-g))) * u;
                sp[nj * 16] = bf1(a);
            }
        }
    }
}

// ---------------- shared expert down proj: MFMA dense (round-0 proven body) ----------------
__global__ __launch_bounds__(256) void down_shared_mfma(
    const unsigned short* __restrict__ sact, const float* __restrict__ Sd,
    float* __restrict__ out)
{
    const int m0 = blockIdx.y * 128;
    const int n0 = blockIdx.x * 64;

    __shared__ unsigned short As[128 * AP];
    __shared__ unsigned short Bs[64 * AP];

    const int tid = threadIdx.x;
    const int lane = tid & 63;
    const int wv = tid >> 6;
    const int lr = lane & 15;
    const int lq = lane >> 4;

    f32x4 acc[2][4];
    #pragma unroll
    for (int i = 0; i < 2; ++i)
        #pragma unroll
        for (int j = 0; j < 4; ++j)
            acc[i][j] = (f32x4){0.f, 0.f, 0.f, 0.f};

    const float* wp = Sd + (size_t)n0 * SI_DIM;
    const int ar = tid >> 4;
    const int ac = (tid & 15) * 4;

    for (int k0 = 0; k0 < SI_DIM; k0 += 64) {
        #pragma unroll
        for (int p = 0; p < 8; ++p) {
            int r = ar + p * 16;
            uint2 v = *(const uint2*)(sact + (size_t)(m0 + r) * SI_DIM + k0 + ac);
            *(uint2*)&As[r * AP + ac] = v;
        }
        #pragma unroll
        for (int p = 0; p < 4; ++p) {
            int r = ar + p * 16;
            float4 w4 = *(const float4*)(wp + (size_t)r * SI_DIM + k0 + ac);
            *(uint2*)&Bs[r * AP + ac] = make_uint2(pk2(w4.x, w4.y), pk2(w4.z, w4.w));
        }
        __syncthreads();
        #pragma unroll
        for (int ks = 0; ks < 2; ++ks) {
            bf16x8 a0 = *(const bf16x8*)&As[(wv * 32 + lr) * AP + ks * 32 + lq * 8];
            bf16x8 a1 = *(const bf16x8*)&As[(wv * 32 + 16 + lr) * AP + ks * 32 + lq * 8];
            #pragma unroll
            for (int nj = 0; nj < 4; ++nj) {
                bf16x8 b = *(const bf16x8*)&Bs[(nj * 16 + lr) * AP + ks * 32 + lq * 8];
                acc[0][nj] = __builtin_amdgcn_mfma_f32_16x16x32_bf16(a0, b, acc[0][nj], 0, 0, 0);
                acc[1][nj] = __builtin_amdgcn_mfma_f32_16x16x32_bf16(a1, b, acc[1][nj], 0, 0, 0);
            }
        }
        __syncthreads();
    }

    #pragma unroll
    for (int mi = 0; mi < 2; ++mi) {
        #pragma unroll
        for (int r = 0; r < 4; ++r) {
            int trow = m0 + wv * 32 + mi * 16 + lq * 4 + r;
            float* op = out + (size_t)trow * H_DIM + n0 + lr;
            #pragma unroll
            for (int nj = 0; nj < 4; ++nj)
                op[nj * 16] = acc[mi][nj][r];
        }
    }
}

// ---------------- launch ----------------
extern "C" void kernel_launch(void* const* d_in, const int* in_sizes, int n_in,
                              void* d_out, int out_size, void* d_ws, size_t ws_size,
                              hipStream_t stream)
{
    const float* x  = (const float*)d_in[0];
    const float* gw = (const float*)d_in[1];
    const float* gb = (const float*)d_in[2];
    const float* Wg = (const float*)d_in[3];
    const float* Wu = (const float*)d_in[4];
    const float* Wd = (const float*)d_in[5];
    const float* Sg = (const float*)d_in[6];
    const float* Su = (const float*)d_in[7];
    const float* Sd = (const float*)d_in[8];
    float* out = (float*)d_out;

    // workspace layout (16B-aligned chunks first)
    float* slot_out = (float*)d_ws;                                   // 8192*1024 f32 (33.5 MB)
    unsigned short* act  = (unsigned short*)(slot_out + (size_t)NSLOT * H_DIM);  // 8192*704 bf16
    unsigned short* sact = act + (size_t)NSLOT * I_DIM;               // 1024*1408 bf16
    int* counts   = (int*)(sact + (size_t)T_TOK * SI_DIM);            // 64
    int* fillc    = counts + 64;                                      // 64
    int* offs     = fillc + 64;                                       // 64
    int* tk_idx   = offs + 64;                                        // 8192
    float* tk_w   = (float*)(tk_idx + NSLOT);                         // 8192
    int* tok_list = (int*)(tk_w + NSLOT);                             // 8192
    float* w_list = (float*)(tok_list + NSLOT);                       // 8192
    int* tk_pos   = (int*)(w_list + NSLOT);                           // 8192
    int* blk_e    = tk_pos + NSLOT;                                   // 128
    int* blk_s0   = blk_e + MAXBLK;                                   // 128
    int* nblk     = blk_s0 + MAXBLK;                                  // 1

    zero_kernel<<<1, 64, 0, stream>>>(counts, fillc);
    route_kernel<<<T_TOK, 64, 0, stream>>>(x, gw, gb, counts, tk_idx, tk_w);
    scan_kernel<<<1, 64, 0, stream>>>(counts, offs, blk_e, blk_s0, nblk);
    fill_kernel<<<4, 256, 0, stream>>>(tk_idx, tk_w, offs, fillc, tok_list, w_list, tk_pos);

    gateup_routed_mfma<<<dim3(11, MAXBLK), 256, 0, stream>>>(
        x, Wg, Wu, offs, counts, tok_list, w_list, blk_e, blk_s0, nblk, act);
    gateup_shared_mfma<<<dim3(22, 8), 256, 0, stream>>>(x, Sg, Su, sact);
    down_shared_mfma<<<dim3(16, 8), 256, 0, stream>>>(sact, Sd, out);
    down_routed_mfma<<<dim3(16, MAXBLK), 256, 0, stream>>>(
        act, Wd, offs, counts, blk_e, blk_s0, nblk, slot_out);
    combine_kernel<<<T_TOK, 256, 0, stream>>>(slot_out, tk_pos, out);
}

// Round 6
// 729.065 us; speedup vs baseline: 1.3664x; 1.1085x over previous
//
#include <hip/hip_runtime.h>
#include <hip/hip_bf16.h>
#include <cstdint>
#include <cstddef>

// ---- problem constants (DeepSeek-V3 MoE config) ----
#define T_TOK 1024
#define H_DIM 1024
#define I_DIM 704
#define E_NUM 64
#define TOPK 8
#define NGRP 8
#define GSIZE 8          // E_NUM / NGRP
#define TOPKG 4
#define SI_DIM 1408
#define RSCALE 2.5f
#define NSLOT (T_TOK * TOPK)           // 8192 routed slots
#define NSLOT2 (NSLOT + 2 * T_TOK)     // + 2 virtual (shared) experts = 10240
#define EV_NUM (E_NUM + 2)             // 64 routed + 2 virtual experts
#define MAXBLK 160                     // >= 128 routed + 16 virtual live (e, s0) entries

#define AP 72            // LDS row pitch in bf16 elems (144 B rows, 2-way max bank aliasing)

typedef short bf16x8 __attribute__((ext_vector_type(8)));
typedef float f32x4 __attribute__((ext_vector_type(4)));

__device__ inline unsigned pk2(float x, float y) {
    __hip_bfloat162 h2 = __float22bfloat162_rn(make_float2(x, y));
    unsigned u; __builtin_memcpy(&u, &h2, 4); return u;
}
__device__ inline unsigned short bf1(float x) {
    __hip_bfloat16 h = __float2bfloat16(x);
    unsigned short u; __builtin_memcpy(&u, &h, 2); return u;
}

// ---------------- routing ----------------
__global__ __launch_bounds__(64) void route_kernel(
    const float* __restrict__ x, const float* __restrict__ gw, const float* __restrict__ gb,
    int* __restrict__ counts, int* __restrict__ tk_idx, float* __restrict__ tk_w)
{
    const int t = blockIdx.x;
    __shared__ float xs[H_DIM];
    __shared__ float raw[E_NUM];
    __shared__ float sc[E_NUM];
    __shared__ float masked[E_NUM];
    __shared__ float gsc[NGRP];
    const int tid = threadIdx.x;

    const float4* xrow = (const float4*)(x + (size_t)t * H_DIM);
    for (int i = tid; i < H_DIM / 4; i += 64) ((float4*)xs)[i] = xrow[i];
    __syncthreads();

    float a = 0.f;
    const float* w = gw + (size_t)tid * H_DIM;
    for (int h = 0; h < H_DIM; h += 4) {
        float4 w4 = *(const float4*)(w + h);
        a += xs[h] * w4.x + xs[h+1] * w4.y + xs[h+2] * w4.z + xs[h+3] * w4.w;
    }
    float s = 1.f / (1.f + expf(-a));
    raw[tid] = s;
    sc[tid] = s + gb[tid];
    __syncthreads();

    if (tid == 0) {
        for (int g = 0; g < NGRP; ++g) {
            float m1 = -1e30f, m2 = -1e30f;
            for (int j = 0; j < GSIZE; ++j) {
                float v = sc[g * GSIZE + j];
                if (v > m1) { m2 = m1; m1 = v; }
                else if (v > m2) { m2 = v; }
            }
            gsc[g] = m1 + m2;
        }
        bool gsel[NGRP];
        for (int g = 0; g < NGRP; ++g) gsel[g] = false;
        for (int k = 0; k < TOPKG; ++k) {
            int best = -1; float bv = -1e30f;
            for (int g = 0; g < NGRP; ++g)
                if (!gsel[g] && gsc[g] > bv) { bv = gsc[g]; best = g; }
            gsel[best] = true;
        }
        for (int e = 0; e < E_NUM; ++e)
            masked[e] = gsel[e / GSIZE] ? sc[e] : 0.0f;
        int idx[TOPK];
        float wsum = 0.f;
        for (int k = 0; k < TOPK; ++k) {
            int best = 0; float bv = -1e30f;
            for (int e = 0; e < E_NUM; ++e)
                if (masked[e] > bv) { bv = masked[e]; best = e; }
            masked[best] = -1e30f;
            idx[k] = best;
            wsum += raw[best];
        }
        float inv = RSCALE / (wsum + 1e-20f);
        for (int k = 0; k < TOPK; ++k) {
            tk_idx[t * TOPK + k] = idx[k];
            tk_w[t * TOPK + k] = raw[idx[k]] * inv;
            atomicAdd(&counts[idx[k]], 1);
        }
    }
}

__global__ void zero_kernel(int* counts, int* fillc)
{
    int i = threadIdx.x;
    if (i < E_NUM) { counts[i] = 0; fillc[i] = 0; }
    if (i >= E_NUM && i < EV_NUM) counts[i] = T_TOK;   // virtual experts: all tokens
}

// scan + dense live-block list (routed + virtual); dispatch front = 100% live
__global__ void scan_kernel(const int* __restrict__ counts, int* __restrict__ offs,
                            int* __restrict__ blk_e, int* __restrict__ blk_s0,
                            int* __restrict__ nblk)
{
    if (threadIdx.x == 0) {
        int acc = 0;
        for (int e = 0; e < E_NUM; ++e) { offs[e] = acc; acc += counts[e]; }
        offs[E_NUM]     = NSLOT;           // virtual expert 0
        offs[E_NUM + 1] = NSLOT + T_TOK;   // virtual expert 1
        int n = 0;
        for (int e = 0; e < EV_NUM; ++e)
            for (int t = 0; t < counts[e]; t += 128) { blk_e[n] = e; blk_s0[n] = t; ++n; }
        nblk[0] = n;
    }
}

__global__ void fill_kernel(const int* __restrict__ tk_idx, const float* __restrict__ tk_w,
                            const int* __restrict__ offs, int* __restrict__ fillc,
                            int* __restrict__ tok_list, float* __restrict__ w_list,
                            int* __restrict__ tk_pos)
{
    int t = blockIdx.x * blockDim.x + threadIdx.x;
    if (t >= T_TOK) return;
    for (int k = 0; k < TOPK; ++k) {
        int e = tk_idx[t * TOPK + k];
        int pos = offs[e] + atomicAdd(&fillc[e], 1);
        tok_list[pos] = t;
        w_list[pos] = tk_w[t * TOPK + k];
        tk_pos[t * TOPK + k] = pos;
    }
    // virtual (shared-expert) slots: identity token, unit weight
    tok_list[NSLOT + t] = t;          w_list[NSLOT + t] = 1.f;
    tok_list[NSLOT + T_TOK + t] = t;  w_list[NSLOT + T_TOK + t] = 1.f;
}

// ---------------- gate/up (routed + shared fused): 8-wave blocks ----------------
// D[m = slot][n = I-col]. Block: 128 slots x 64 I-cols, wave wv owns slot rows wv*16..+16.
__global__ __launch_bounds__(512) void gateup_mfma(
    const float* __restrict__ x, const float* __restrict__ Wg, const float* __restrict__ Wu,
    const float* __restrict__ Sg, const float* __restrict__ Su,
    const int* __restrict__ offs, const int* __restrict__ counts,
    const int* __restrict__ tok_list, const float* __restrict__ w_list,
    const int* __restrict__ blk_e, const int* __restrict__ blk_s0, const int* __restrict__ nblk,
    unsigned short* __restrict__ act)
{
    const int by = blockIdx.y;
    if (by >= nblk[0]) return;
    const int e = blk_e[by];
    const int m0 = blk_s0[by];
    const int cnt = counts[e];
    const int off = offs[e];
    const int n0 = blockIdx.x * 64;

    __shared__ unsigned short As[128 * AP];
    __shared__ unsigned short Bg[64 * AP];
    __shared__ unsigned short Bu[64 * AP];
    __shared__ int toks[128];
    __shared__ float wts[128];

    const int tid = threadIdx.x;
    if (tid < 128) {
        int s = m0 + tid;
        toks[tid] = (s < cnt) ? tok_list[off + s] : -1;
        wts[tid]  = (s < cnt) ? w_list[off + s] : 0.f;
    }
    __syncthreads();

    const int lane = tid & 63;
    const int wv = tid >> 6;           // 0..7
    const int lr = lane & 15;
    const int lq = lane >> 4;

    f32x4 accg[4], accu[4];
    #pragma unroll
    for (int j = 0; j < 4; ++j) {
        accg[j] = (f32x4){0.f, 0.f, 0.f, 0.f};
        accu[j] = (f32x4){0.f, 0.f, 0.f, 0.f};
    }

    // weight base: routed experts use Wg/Wu, virtual experts use Sg/Su halves
    const float* wgp = (e < E_NUM)
        ? Wg + (size_t)e * I_DIM * H_DIM + (size_t)n0 * H_DIM
        : Sg + (size_t)(e - E_NUM) * I_DIM * H_DIM + (size_t)n0 * H_DIM;
    const float* wup = (e < E_NUM)
        ? Wu + (size_t)e * I_DIM * H_DIM + (size_t)n0 * H_DIM
        : Su + (size_t)(e - E_NUM) * I_DIM * H_DIM + (size_t)n0 * H_DIM;

    const int ar = tid >> 4;          // 0..31
    const int ac = (tid & 15) * 4;    // 0..60

    for (int k0 = 0; k0 < H_DIM; k0 += 64) {
        // tokens: 128 rows x 64 cols, 4 float4 per thread
        #pragma unroll
        for (int p = 0; p < 4; ++p) {
            int r = ar + p * 32;
            int tkn = toks[r];
            float4 v = make_float4(0.f, 0.f, 0.f, 0.f);
            if (tkn >= 0) v = *(const float4*)(x + (size_t)tkn * H_DIM + k0 + ac);
            *(uint2*)&As[r * AP + ac] = make_uint2(pk2(v.x, v.y), pk2(v.z, v.w));
        }
        // weights: 64 rows x 64 cols x2, 2 float4 per thread each
        #pragma unroll
        for (int p = 0; p < 2; ++p) {
            int r = ar + p * 32;
            float4 g = *(const float4*)(wgp + (size_t)r * H_DIM + k0 + ac);
            *(uint2*)&Bg[r * AP + ac] = make_uint2(pk2(g.x, g.y), pk2(g.z, g.w));
            float4 u = *(const float4*)(wup + (size_t)r * H_DIM + k0 + ac);
            *(uint2*)&Bu[r * AP + ac] = make_uint2(pk2(u.x, u.y), pk2(u.z, u.w));
        }
        __syncthreads();
        #pragma unroll
        for (int ks = 0; ks < 2; ++ks) {
            bf16x8 a = *(const bf16x8*)&As[(wv * 16 + lr) * AP + ks * 32 + lq * 8];
            #pragma unroll
            for (int nj = 0; nj < 4; ++nj) {
                bf16x8 bg = *(const bf16x8*)&Bg[(nj * 16 + lr) * AP + ks * 32 + lq * 8];
                bf16x8 bu = *(const bf16x8*)&Bu[(nj * 16 + lr) * AP + ks * 32 + lq * 8];
                accg[nj] = __builtin_amdgcn_mfma_f32_16x16x32_bf16(a, bg, accg[nj], 0, 0, 0);
                accu[nj] = __builtin_amdgcn_mfma_f32_16x16x32_bf16(a, bu, accu[nj], 0, 0, 0);
            }
        }
        __syncthreads();
    }

    #pragma unroll
    for (int r = 0; r < 4; ++r) {
        int srow = wv * 16 + lq * 4 + r;
        if (m0 + srow < cnt) {
            float w = wts[srow];
            unsigned short* ap = act + (size_t)(off + m0 + srow) * I_DIM + n0 + lr;
            #pragma unroll
            for (int nj = 0; nj < 4; ++nj) {
                float g = accg[nj][r];
                float u = accu[nj][r];
                float a = w * (g / (1.f + __expf(-g))) * u;
                ap[nj * 16] = bf1(a);
            }
        }
    }
}

// ---------------- down proj (routed + shared fused): 8-wave blocks, slot_out stores ----------------
// D[m = slot][n = H-col]. Block: 128 slots x 64 H-cols.
__global__ __launch_bounds__(512) void down_mfma(
    const unsigned short* __restrict__ act, const float* __restrict__ Wd,
    const float* __restrict__ Sd,
    const int* __restrict__ offs, const int* __restrict__ counts,
    const int* __restrict__ blk_e, const int* __restrict__ blk_s0, const int* __restrict__ nblk,
    float* __restrict__ slot_out)
{
    const int by = blockIdx.y;
    if (by >= nblk[0]) return;
    const int e = blk_e[by];
    const int m0 = blk_s0[by];
    const int cnt = counts[e];
    const int off = offs[e];
    const int n0 = blockIdx.x * 64;

    __shared__ unsigned short As[128 * AP];
    __shared__ unsigned short Bs[64 * AP];

    const int tid = threadIdx.x;
    const int lane = tid & 63;
    const int wv = tid >> 6;
    const int lr = lane & 15;
    const int lq = lane >> 4;

    f32x4 acc[4];
    #pragma unroll
    for (int j = 0; j < 4; ++j)
        acc[j] = (f32x4){0.f, 0.f, 0.f, 0.f};

    // weight rows n0..n0+63; routed: Wd [H][I] pitch I_DIM; virtual: Sd [H][SI] pitch SI_DIM, col-offset
    const float* wdp;
    size_t wpitch;
    if (e < E_NUM) {
        wdp = Wd + (size_t)e * H_DIM * I_DIM + (size_t)n0 * I_DIM;
        wpitch = I_DIM;
    } else {
        wdp = Sd + (size_t)n0 * SI_DIM + (size_t)(e - E_NUM) * I_DIM;
        wpitch = SI_DIM;
    }
    const unsigned short* ap0 = act + (size_t)(off + m0) * I_DIM;
    const int ar = tid >> 4;          // 0..31
    const int ac = (tid & 15) * 4;    // 0..60

    for (int k0 = 0; k0 < I_DIM; k0 += 64) {
        #pragma unroll
        for (int p = 0; p < 4; ++p) {
            int r = ar + p * 32;
            uint2 v = make_uint2(0u, 0u);
            if (m0 + r < cnt) v = *(const uint2*)(ap0 + (size_t)r * I_DIM + k0 + ac);
            *(uint2*)&As[r * AP + ac] = v;
        }
        #pragma unroll
        for (int p = 0; p < 2; ++p) {
            int r = ar + p * 32;
            float4 w4 = *(const float4*)(wdp + (size_t)r * wpitch + k0 + ac);
            *(uint2*)&Bs[r * AP + ac] = make_uint2(pk2(w4.x, w4.y), pk2(w4.z, w4.w));
        }
        __syncthreads();
        #pragma unroll
        for (int ks = 0; ks < 2; ++ks) {
            bf16x8 a = *(const bf16x8*)&As[(wv * 16 + lr) * AP + ks * 32 + lq * 8];
            #pragma unroll
            for (int nj = 0; nj < 4; ++nj) {
                bf16x8 b = *(const bf16x8*)&Bs[(nj * 16 + lr) * AP + ks * 32 + lq * 8];
                acc[nj] = __builtin_amdgcn_mfma_f32_16x16x32_bf16(a, b, acc[nj], 0, 0, 0);
            }
        }
        __syncthreads();
    }

    #pragma unroll
    for (int r = 0; r < 4; ++r) {
        int srow = wv * 16 + lq * 4 + r;
        if (m0 + srow < cnt) {
            float* op = slot_out + (size_t)(off + m0 + srow) * H_DIM + n0 + lr;
            #pragma unroll
            for (int nj = 0; nj < 4; ++nj)
                op[nj * 16] = acc[nj][r];
        }
    }
}

// ---------------- combine: out[t] = sum over TOPK routed + 2 virtual slots ----------------
__global__ __launch_bounds__(256) void combine_kernel(
    const float* __restrict__ slot_out, const int* __restrict__ tk_pos,
    float* __restrict__ out)
{
    const int t = blockIdx.x;
    __shared__ int pos[TOPK + 2];
    if (threadIdx.x < TOPK) pos[threadIdx.x] = tk_pos[t * TOPK + threadIdx.x];
    else if (threadIdx.x == TOPK)     pos[TOPK]     = NSLOT + t;
    else if (threadIdx.x == TOPK + 1) pos[TOPK + 1] = NSLOT + T_TOK + t;
    __syncthreads();
    const int i = threadIdx.x;   // 256 threads x float4 = 1024 floats
    float4 a = make_float4(0.f, 0.f, 0.f, 0.f);
    #pragma unroll
    for (int k = 0; k < TOPK + 2; ++k) {
        float4 v = ((const float4*)(slot_out + (size_t)pos[k] * H_DIM))[i];
        a.x += v.x; a.y += v.y; a.z += v.z; a.w += v.w;
    }
    ((float4*)(out + (size_t)t * H_DIM))[i] = a;
}

// ---------------- launch ----------------
extern "C" void kernel_launch(void* const* d_in, const int* in_sizes, int n_in,
                              void* d_out, int out_size, void* d_ws, size_t ws_size,
                              hipStream_t stream)
{
    const float* x  = (const float*)d_in[0];
    const float* gw = (const float*)d_in[1];
    const float* gb = (const float*)d_in[2];
    const float* Wg = (const float*)d_in[3];
    const float* Wu = (const float*)d_in[4];
    const float* Wd = (const float*)d_in[5];
    const float* Sg = (const float*)d_in[6];
    const float* Su = (const float*)d_in[7];
    const float* Sd = (const float*)d_in[8];
    float* out = (float*)d_out;

    // workspace layout (16B-aligned chunks first)
    float* slot_out = (float*)d_ws;                                   // NSLOT2*1024 f32 (41.9 MB)
    unsigned short* act  = (unsigned short*)(slot_out + (size_t)NSLOT2 * H_DIM);  // NSLOT2*704 bf16 (14.4 MB)
    int* counts   = (int*)(act + (size_t)NSLOT2 * I_DIM);             // 66
    int* fillc    = counts + EV_NUM;                                  // 64
    int* offs     = fillc + 64;                                       // 66
    int* tk_idx   = offs + EV_NUM;                                    // 8192
    float* tk_w   = (float*)(tk_idx + NSLOT);                         // 8192
    int* tok_list = (int*)(tk_w + NSLOT);                             // 10240
    float* w_list = (float*)(tok_list + NSLOT2);                      // 10240
    int* tk_pos   = (int*)(w_list + NSLOT2);                          // 8192
    int* blk_e    = tk_pos + NSLOT;                                   // 160
    int* blk_s0   = blk_e + MAXBLK;                                   // 160
    int* nblk     = blk_s0 + MAXBLK;                                  // 1

    zero_kernel<<<1, 128, 0, stream>>>(counts, fillc);
    route_kernel<<<T_TOK, 64, 0, stream>>>(x, gw, gb, counts, tk_idx, tk_w);
    scan_kernel<<<1, 64, 0, stream>>>(counts, offs, blk_e, blk_s0, nblk);
    fill_kernel<<<4, 256, 0, stream>>>(tk_idx, tk_w, offs, fillc, tok_list, w_list, tk_pos);

    gateup_mfma<<<dim3(11, MAXBLK), 512, 0, stream>>>(
        x, Wg, Wu, Sg, Su, offs, counts, tok_list, w_list, blk_e, blk_s0, nblk, act);
    down_mfma<<<dim3(16, MAXBLK), 512, 0, stream>>>(
        act, Wd, Sd, offs, counts, blk_e, blk_s0, nblk, slot_out);
    combine_kernel<<<T_TOK, 256, 0, stream>>>(slot_out, tk_pos, out);
}